// Round 1
// baseline (33012.894 us; speedup 1.0000x reference)
//
#include <hip/hip_runtime.h>
#include <math.h>

#define SQH 0.70710678118654752f

// ---------------------------------------------------------------------------
// upsample: transposed conv, kernel (3,32), lhs_dilation 16 in width.
// out[oh,ow] = b + sum_{kh,m} w[2-kh][31-(kw0+16m)] * in[oh-1+kh][(ow-23+kw0+16m)/16]
// ---------------------------------------------------------------------------
__global__ void upsample_k(const float* __restrict__ in, int Tin,
                           const float* __restrict__ w, const float* __restrict__ bb,
                           float* __restrict__ out, int Tout)
{
    int idx = blockIdx.x * 256 + threadIdx.x;
    if (idx >= 80 * Tout) return;
    int oh = idx / Tout, ow = idx - oh * Tout;
    float acc = bb[0];
    int kw0 = (23 - (ow & 15)) & 15;
#pragma unroll
    for (int kh = 0; kh < 3; ++kh) {
        int ih = oh - 1 + kh;
        if (ih < 0 || ih >= 80) continue;
#pragma unroll
        for (int m = 0; m < 2; ++m) {
            int kw = kw0 + 16 * m;
            int j = ow - 23 + kw;
            if (j < 0) continue;
            int src = j >> 4;
            if (src < Tin)
                acc = fmaf(w[(2 - kh) * 32 + (31 - kw)], in[ih * Tin + src], acc);
        }
    }
    out[idx] = acc > 0.f ? acc : 0.4f * acc;
}

// squeeze c_up [80][32768] -> c2f [80][16][2048] : c2f[cc][i][j] = cup[cc][j*16+i]
__global__ void squeeze_c_k(const float* __restrict__ cup, float* __restrict__ c2f)
{
    int idx = blockIdx.x * 256 + threadIdx.x;   // 80*32768
    int cc = idx >> 15, rem = idx & 32767;
    int i = rem >> 11, j = rem & 2047;
    c2f[idx] = cup[(cc << 15) + (j << 4) + i];
}

// squeeze x [32768] -> out0 [16][2048]
__global__ void squeeze_x_k(const float* __restrict__ x, float* __restrict__ o)
{
    int idx = blockIdx.x * 256 + threadIdx.x;   // 32768
    int i = idx >> 11, j = idx & 2047;
    o[idx] = x[(j << 4) + i];
}

__global__ void zero_k(float* p)
{
    if (threadIdx.x == 0 && blockIdx.x == 0) p[0] = 0.f;
}

// front 1x1 conv: h[ch][r][t] = fw[ch]*X[r][t] + fb[ch]  (r in 0..14)
// also zeroes lsacc (2*30720 floats)
__global__ void front_k(const float* __restrict__ X, float* __restrict__ h,
                        const float* __restrict__ fw, const float* __restrict__ fb,
                        float* __restrict__ lsacc)
{
    int idx = blockIdx.x * 256 + threadIdx.x;
    if (idx < 983040) {                 // 128 ch * 7680 float4
        int ch = idx / 7680, rt4 = idx - ch * 7680;
        float4 xv = ((const float4*)X)[rt4];
        float wv = fw[ch], bv = fb[ch];
        float4 o = make_float4(fmaf(wv, xv.x, bv), fmaf(wv, xv.y, bv),
                               fmaf(wv, xv.z, bv), fmaf(wv, xv.w, bv));
        ((float4*)h)[ch * 7680 + rt4] = o;
    } else {
        ((float4*)lsacc)[idx - 983040] = make_float4(0.f, 0.f, 0.f, 0.f);
    }
}

// ---------------------------------------------------------------------------
// Main dilated causal conv + conditioning + gated activation.
// Block: 256 thr = 16 (t-cols, 4 t each) x 16 (ocp-rows, 4 oc-pairs each).
// Tile: 64 oc-pairs (z-grid of 2) x 64 t x 1 r.
// hg[oc][r][t] = fgb[oc]+fgcb[oc]
//             + sum_{ic,kh,kw} fgw[oc][ic][kh][kw]*h[ic][r-(2-kh)dh][t+(kw-1)dw]
//             + sum_cc fgcw[oc][cc]*c2[cc][rrow][t]
// oact[p] = tanh(hg[p]) * sigmoid(hg[p+128])
// ---------------------------------------------------------------------------
__global__ __launch_bounds__(256, 2)
void conv_gate_k(const float* __restrict__ h, const float* __restrict__ c2,
                 const float* __restrict__ fgw, const float* __restrict__ fgb,
                 const float* __restrict__ fgcw, const float* __restrict__ fgcb,
                 float* __restrict__ oact, int dh, int dw, int rev)
{
    __shared__ __align__(16) float hS[4608];    // [icc 8][tap 9][tt 64]
    __shared__ __align__(16) float wS[9216];    // [half 2][icc 8][tap 9][p 64]
    __shared__ __align__(16) float cS[512];     // [jc 8][tt 64]
    __shared__ __align__(16) float wcS[1024];   // [half 2][jc 8][p 64]

    const int tid  = threadIdx.x;
    const int t0   = blockIdx.x << 6;
    const int r    = blockIdx.y;
    const int ocb  = blockIdx.z << 6;
    const int col4 = (tid & 15) << 2;
    const int pr4  = ((tid >> 4) << 2);

    float a0[4][4], a1[4][4];
#pragma unroll
    for (int p = 0; p < 4; ++p) {
        int oc = ocb + pr4 + p;
        float b0 = fgb[oc] + fgcb[oc];
        float b1 = fgb[oc + 128] + fgcb[oc + 128];
#pragma unroll
        for (int j = 0; j < 4; ++j) { a0[p][j] = b0; a1[p][j] = b1; }
    }

    for (int ic0 = 0; ic0 < 128; ic0 += 8) {
        __syncthreads();
        // stage h taps
#pragma unroll
        for (int e = 0; e < 18; ++e) {
            int idx = tid + (e << 8);
            int tt = idx & 63;
            int tap = (idx >> 6) % 9;
            int icc = idx / 576;
            int kh = tap / 3, kw = tap - kh * 3;
            int rr = r - (2 - kh) * dh;
            int cc = t0 + tt + (kw - 1) * dw;
            float v = 0.f;
            if (rr >= 0 && cc >= 0 && cc < 2048)
                v = h[(ic0 + icc) * 30720 + rr * 2048 + cc];
            hS[idx] = v;
        }
        // stage weights (p-fastest: conflict-free LDS writes; fgw is L2-hot)
#pragma unroll
        for (int e = 0; e < 36; ++e) {
            int idx = tid + (e << 8);
            int p = idx & 63;
            int tap = (idx >> 6) % 9;
            int icc = (idx / 576) & 7;
            int half = idx / 4608;
            int oc = ocb + p + (half << 7);
            wS[idx] = fgw[oc * 1152 + (ic0 + icc) * 9 + tap];
        }
        __syncthreads();
#pragma unroll
        for (int icc = 0; icc < 8; ++icc) {
#pragma unroll
            for (int tap = 0; tap < 9; ++tap) {
                const int base = (icc * 9 + tap) << 6;
                const float4 hq  = *(const float4*)&hS[base + col4];
                const float4 w0q = *(const float4*)&wS[base + pr4];
                const float4 w1q = *(const float4*)&wS[4608 + base + pr4];
                float hv[4] = {hq.x, hq.y, hq.z, hq.w};
                float w0[4] = {w0q.x, w0q.y, w0q.z, w0q.w};
                float w1[4] = {w1q.x, w1q.y, w1q.z, w1q.w};
#pragma unroll
                for (int p = 0; p < 4; ++p)
#pragma unroll
                    for (int j = 0; j < 4; ++j) {
                        a0[p][j] = fmaf(w0[p], hv[j], a0[p][j]);
                        a1[p][j] = fmaf(w1[p], hv[j], a1[p][j]);
                    }
            }
        }
    }

    // conditioning 1x1 over 80 mel channels; rrow folds the per-flow reversal
    const int rrow = rev ? (14 - r) : (r + 1);
    for (int cc0 = 0; cc0 < 80; cc0 += 8) {
        __syncthreads();
#pragma unroll
        for (int e = 0; e < 2; ++e) {
            int idx = tid + (e << 8);
            int tt = idx & 63, jc = idx >> 6;
            cS[idx] = c2[(cc0 + jc) * 32768 + rrow * 2048 + t0 + tt];
        }
#pragma unroll
        for (int e = 0; e < 4; ++e) {
            int idx = tid + (e << 8);
            int p = idx & 63, jc = (idx >> 6) & 7, half = idx >> 9;
            wcS[idx] = fgcw[(ocb + p + (half << 7)) * 80 + cc0 + jc];
        }
        __syncthreads();
#pragma unroll
        for (int jc = 0; jc < 8; ++jc) {
            const float4 cq  = *(const float4*)&cS[(jc << 6) + col4];
            const float4 w0q = *(const float4*)&wcS[(jc << 6) + pr4];
            const float4 w1q = *(const float4*)&wcS[512 + (jc << 6) + pr4];
            float hv[4] = {cq.x, cq.y, cq.z, cq.w};
            float w0[4] = {w0q.x, w0q.y, w0q.z, w0q.w};
            float w1[4] = {w1q.x, w1q.y, w1q.z, w1q.w};
#pragma unroll
            for (int p = 0; p < 4; ++p)
#pragma unroll
                for (int j = 0; j < 4; ++j) {
                    a0[p][j] = fmaf(w0[p], hv[j], a0[p][j]);
                    a1[p][j] = fmaf(w1[p], hv[j], a1[p][j]);
                }
        }
    }

    // gated activation + store
#pragma unroll
    for (int p = 0; p < 4; ++p) {
        int ocp = ocb + pr4 + p;
        float4 o;
        o.x = tanhf(a0[p][0]) * (1.f / (1.f + expf(-a1[p][0])));
        o.y = tanhf(a0[p][1]) * (1.f / (1.f + expf(-a1[p][1])));
        o.z = tanhf(a0[p][2]) * (1.f / (1.f + expf(-a1[p][2])));
        o.w = tanhf(a0[p][3]) * (1.f / (1.f + expf(-a1[p][3])));
        *(float4*)&oact[ocp * 30720 + r * 2048 + t0 + col4] = o;
    }
}

// ---------------------------------------------------------------------------
// h = (h + rs_w @ oact + rs_b) * sqrt(0.5).  Tile: 128 ch x 64 t x 1 r.
// ---------------------------------------------------------------------------
__global__ __launch_bounds__(256, 4)
void rs_update_k(float* __restrict__ h, const float* __restrict__ oact,
                 const float* __restrict__ rsw, const float* __restrict__ rsb)
{
    __shared__ __align__(16) float aS[1024];    // [icc 16][tt 64]
    __shared__ __align__(16) float wSr[2048];   // [icc 16][ch 128]
    const int tid = threadIdx.x;
    const int t0 = blockIdx.x << 6;
    const int r = blockIdx.y;
    const int col4 = (tid & 15) << 2;
    const int ch0 = (tid >> 4) << 3;

    float acc[8][4];
#pragma unroll
    for (int p = 0; p < 8; ++p)
#pragma unroll
        for (int j = 0; j < 4; ++j) acc[p][j] = 0.f;

    for (int ic0 = 0; ic0 < 128; ic0 += 16) {
        __syncthreads();
#pragma unroll
        for (int e = 0; e < 4; ++e) {
            int idx = tid + (e << 8);
            aS[idx] = oact[(ic0 + (idx >> 6)) * 30720 + r * 2048 + t0 + (idx & 63)];
        }
#pragma unroll
        for (int e = 0; e < 8; ++e) {
            int idx = tid + (e << 8);
            int ch = idx & 127, icc = idx >> 7;
            wSr[idx] = rsw[ch * 128 + ic0 + icc];
        }
        __syncthreads();
#pragma unroll
        for (int icc = 0; icc < 16; ++icc) {
            const float4 aq  = *(const float4*)&aS[(icc << 6) + col4];
            const float4 w0q = *(const float4*)&wSr[(icc << 7) + ch0];
            const float4 w1q = *(const float4*)&wSr[(icc << 7) + ch0 + 4];
            float av[4] = {aq.x, aq.y, aq.z, aq.w};
            float wv[8] = {w0q.x, w0q.y, w0q.z, w0q.w, w1q.x, w1q.y, w1q.z, w1q.w};
#pragma unroll
            for (int p = 0; p < 8; ++p)
#pragma unroll
                for (int j = 0; j < 4; ++j)
                    acc[p][j] = fmaf(wv[p], av[j], acc[p][j]);
        }
    }
#pragma unroll
    for (int p = 0; p < 8; ++p) {
        int ch = ch0 + p;
        float4* hp = (float4*)&h[ch * 30720 + r * 2048 + t0 + col4];
        float4 hv = *hp;
        float bv = rsb[ch];
        hv.x = (hv.x + acc[p][0] + bv) * SQH;
        hv.y = (hv.y + acc[p][1] + bv) * SQH;
        hv.z = (hv.z + acc[p][2] + bv) * SQH;
        hv.w = (hv.w + acc[p][3] + bv) * SQH;
        *hp = hv;
    }
}

// lsacc[k][r][t] += proj_w[k] . oact[:,r,t]   (incremental skip projection)
__global__ void lsadd_k(float* __restrict__ lsacc, const float* __restrict__ oact,
                        const float* __restrict__ pw)
{
    int idx = blockIdx.x * 256 + threadIdx.x;   // < 30720
    float a0 = 0.f, a1 = 0.f;
#pragma unroll 4
    for (int ic = 0; ic < 128; ++ic) {
        float v = oact[ic * 30720 + idx];
        a0 = fmaf(pw[ic], v, a0);
        a1 = fmaf(pw[128 + ic], v, a1);
    }
    lsacc[idx] += a0;
    lsacc[30720 + idx] += a1;
}

// affine coupling update + fold the end-of-flow height reversal + logdet
__global__ void update_k(const float* __restrict__ Xc, float* __restrict__ Xn,
                         const float* __restrict__ lsacc, const float* __restrict__ pb,
                         const float* __restrict__ psc, float* __restrict__ logdet)
{
    int idx = blockIdx.x * 256 + threadIdx.x;   // 30720
    int rr = idx >> 11, t = idx & 2047;
    float e0 = expf(3.f * psc[0]), e1 = expf(3.f * psc[1]);
    float ls0 = (lsacc[idx] + pb[0]) * e0;
    float ls1 = (lsacc[30720 + idx] + pb[1]) * e1;
    float xn = fmaf(Xc[idx + 2048], expf(ls0), ls1);
    Xn[(14 - rr) * 2048 + t] = xn;              // pre-reversed write
    if (idx < 2048) Xn[15 * 2048 + idx] = Xc[idx];
    float s = ls0;
#pragma unroll
    for (int o = 32; o > 0; o >>= 1) s += __shfl_down(s, o);
    if ((threadIdx.x & 63) == 0) atomicAdd(logdet, s);
}

// ---------------------------------------------------------------------------
extern "C" void kernel_launch(void* const* d_in, const int* in_sizes, int n_in,
                              void* d_out, int out_size, void* d_ws, size_t ws_size,
                              hipStream_t stream)
{
    const float* x       = (const float*)d_in[0];
    const float* c       = (const float*)d_in[1];
    const float* front_w = (const float*)d_in[2];
    const float* front_b = (const float*)d_in[3];
    const float* fg_w    = (const float*)d_in[4];
    const float* fg_b    = (const float*)d_in[5];
    const float* fgc_w   = (const float*)d_in[6];
    const float* fgc_b   = (const float*)d_in[7];
    const float* rs_w    = (const float*)d_in[8];
    const float* rs_b    = (const float*)d_in[9];
    const float* proj_w  = (const float*)d_in[10];
    const float* proj_b  = (const float*)d_in[11];
    const float* proj_s  = (const float*)d_in[12];
    const float* up_w1   = (const float*)d_in[13];
    const float* up_b1   = (const float*)d_in[14];
    const float* up_w2   = (const float*)d_in[15];
    const float* up_b2   = (const float*)d_in[16];
    float* out = (float*)d_out;

    float* ws   = (float*)d_ws;
    float* c1   = ws;                  // 80*2048      = 163840
    float* cup  = c1 + 163840;         // 80*32768     = 2621440
    float* c2f  = cup + 2621440;       // 80*16*2048   = 2621440
    float* h    = c2f + 2621440;       // 128*15*2048  = 3932160
    float* oact = h + 3932160;         // 128*15*2048  = 3932160
    float* lsac = oact + 3932160;      // 2*15*2048    = 61440
    float* outA = lsac + 61440;        // 16*2048
    float* outB = outA + 32768;        // 16*2048

    upsample_k<<<640, 256, 0, stream>>>(c, 128, up_w1, up_b1, c1, 2048);
    upsample_k<<<10240, 256, 0, stream>>>(c1, 2048, up_w2, up_b2, cup, 32768);
    squeeze_c_k<<<10240, 256, 0, stream>>>(cup, c2f);
    squeeze_x_k<<<128, 256, 0, stream>>>(x, outA);
    zero_k<<<1, 64, 0, stream>>>(out + 32768);

    float* Xc = outA;
    float* Xn = outB;
    for (int i = 0; i < 8; ++i) {
        int rev = i & 1;
        front_k<<<3900, 256, 0, stream>>>(Xc, h, front_w + i * 128, front_b + i * 128, lsac);
        for (int l = 0; l < 8; ++l) {
            int fl = i * 8 + l;
            int dh = 1 << (l % 3), dw = 1 << l;
            conv_gate_k<<<dim3(32, 15, 2), 256, 0, stream>>>(
                h, c2f,
                fg_w + (size_t)fl * 256 * 1152, fg_b + fl * 256,
                fgc_w + (size_t)fl * 256 * 80, fgc_b + fl * 256,
                oact, dh, dw, rev);
            lsadd_k<<<120, 256, 0, stream>>>(lsac, oact, proj_w + i * 256);
            if (l < 7)
                rs_update_k<<<dim3(32, 15), 256, 0, stream>>>(
                    h, oact, rs_w + (size_t)fl * 16384, rs_b + fl * 128);
        }
        float* dst = (i == 7) ? out : Xn;
        update_k<<<120, 256, 0, stream>>>(Xc, dst, lsac, proj_b + i * 2,
                                          proj_s + i * 2, out + 32768);
        float* tmp = Xc; Xc = Xn; Xn = tmp;
    }
}

// Round 3
// 6416.558 us; speedup vs baseline: 5.1450x; 5.1450x over previous
//
#include <hip/hip_runtime.h>
#include <math.h>

#define SQH 0.70710678118654752f
typedef unsigned short u16;
using bf16x8 = __attribute__((ext_vector_type(8))) short;
using f32x4  = __attribute__((ext_vector_type(4))) float;

__device__ __forceinline__ u16 bfhi(float v) {
    unsigned u = __builtin_bit_cast(unsigned, v);
    return (u16)((u + 0x7FFFu + ((u >> 16) & 1u)) >> 16);
}
__device__ __forceinline__ float bf2f(u16 h) {
    unsigned u = ((unsigned)h) << 16;
    return __builtin_bit_cast(float, u);
}
__device__ __forceinline__ void split2(float v, u16& hi, u16& lo) {
    hi = bfhi(v);
    lo = bfhi(v - bf2f(hi));
}
__device__ __forceinline__ void gl_lds16(const void* g, void* l) {
    __builtin_amdgcn_global_load_lds(
        (const __attribute__((address_space(1))) unsigned*)g,
        (__attribute__((address_space(3))) unsigned*)l, 16, 0, 0);
}

// ---------------------------------------------------------------------------
// upsample: transposed conv, kernel (3,32), lhs_dilation 16 in width.
// ---------------------------------------------------------------------------
__global__ void upsample_k(const float* __restrict__ in, int Tin,
                           const float* __restrict__ w, const float* __restrict__ bb,
                           float* __restrict__ out, int Tout)
{
    int idx = blockIdx.x * 256 + threadIdx.x;
    if (idx >= 80 * Tout) return;
    int oh = idx / Tout, ow = idx - oh * Tout;
    float acc = bb[0];
    int kw0 = (23 - (ow & 15)) & 15;
#pragma unroll
    for (int kh = 0; kh < 3; ++kh) {
        int ih = oh - 1 + kh;
        if (ih < 0 || ih >= 80) continue;
#pragma unroll
        for (int m = 0; m < 2; ++m) {
            int kw = kw0 + 16 * m;
            int j = ow - 23 + kw;
            if (j < 0) continue;
            int src = j >> 4;
            if (src < Tin)
                acc = fmaf(w[(2 - kh) * 32 + (31 - kw)], in[ih * Tin + src], acc);
        }
    }
    out[idx] = acc > 0.f ? acc : 0.4f * acc;
}

__global__ void squeeze_x_k(const float* __restrict__ x, float* __restrict__ o)
{
    int idx = blockIdx.x * 256 + threadIdx.x;
    int i = idx >> 11, j = idx & 2047;
    o[idx] = x[(j << 4) + i];
}

__global__ void zero2_k(float* __restrict__ logdet, float* __restrict__ zbuf)
{
    if (threadIdx.x == 0) logdet[0] = 0.f;
    zbuf[threadIdx.x] = 0.f;
}

// c2T[r][t][96cc] hi/lo bf16, zero-padded 80->96
__global__ void c2t_k(const float* __restrict__ cup, u16* __restrict__ THi, u16* __restrict__ TLo)
{
    int idx = blockIdx.x * 256 + threadIdx.x;   // 16*2048*96
    int cc = idx % 96; int rt = idx / 96; int t = rt & 2047; int rr = rt >> 11;
    float v = (cc < 80) ? cup[(size_t)cc * 32768 + t * 16 + rr] : 0.f;
    u16 hi, lo; split2(v, hi, lo);
    THi[idx] = hi; TLo[idx] = lo;
}

// per-flow conv weights -> Wc[l][tap][s][ic] hi/lo (s = gate-permuted oc)
__global__ void wc_cvt_k(const float* __restrict__ fgw, u16* __restrict__ WHi, u16* __restrict__ WLo)
{
    int idx = blockIdx.x * 256 + threadIdx.x;   // 8*256*128
    int ic = idx & 127, s = (idx >> 7) & 255, l = idx >> 15;
    int oc = ((s >> 7) << 6) + (((s >> 6) & 1) << 5) + (s & 31) + (((s >> 5) & 1) << 7);
    const float* src = fgw + ((size_t)(l * 256 + oc) * 128 + ic) * 9;
#pragma unroll
    for (int tap = 0; tap < 9; ++tap) {
        u16 hi, lo; split2(src[tap], hi, lo);
        size_t o = ((size_t)(l * 9 + tap) * 256 + s) * 128 + ic;
        WHi[o] = hi; WLo[o] = lo;
    }
}

// cond weights -> Wd[fl][s][96] hi/lo (all 64 layers)
__global__ void wd_cvt_k(const float* __restrict__ fgcw, u16* __restrict__ WHi, u16* __restrict__ WLo)
{
    int idx = blockIdx.x * 256 + threadIdx.x;   // 64*256*96
    int cc = idx % 96; int rest = idx / 96; int s = rest & 255; int fl = rest >> 8;
    int oc = ((s >> 7) << 6) + (((s >> 6) & 1) << 5) + (s & 31) + (((s >> 5) & 1) << 7);
    float v = (cc < 80) ? fgcw[((size_t)fl * 256 + oc) * 80 + cc] : 0.f;
    u16 hi, lo; split2(v, hi, lo);
    WHi[idx] = hi; WLo[idx] = lo;
}

__global__ void wrs_cvt_k(const float* __restrict__ rsw, u16* __restrict__ WHi, u16* __restrict__ WLo)
{
    int idx = blockIdx.x * 256 + threadIdx.x;   // 64*16384
    u16 hi, lo; split2(rsw[idx], hi, lo);
    WHi[idx] = hi; WLo[idx] = lo;
}

// front 1x1: h fp32 [ch][rt] + hT hi/lo [rt][128ch]; zeroes lsacc
__global__ void front_k(const float* __restrict__ X, float* __restrict__ h,
                        u16* __restrict__ hTHi, u16* __restrict__ hTLo,
                        const float* __restrict__ fw, const float* __restrict__ fb,
                        float* __restrict__ lsacc)
{
    int bid = blockIdx.x, tid = threadIdx.x;
    if (bid < 960) {
        int rt = bid * 32 + (tid >> 3);
        int ch0 = (tid & 7) << 4;
        float xv = X[rt];
        unsigned hs[8], ls[8];
#pragma unroll
        for (int k = 0; k < 16; k += 2) {
            float v0 = fmaf(fw[ch0 + k], xv, fb[ch0 + k]);
            float v1 = fmaf(fw[ch0 + k + 1], xv, fb[ch0 + k + 1]);
            h[(size_t)(ch0 + k) * 30720 + rt] = v0;
            h[(size_t)(ch0 + k + 1) * 30720 + rt] = v1;
            u16 h0, l0, h1, l1; split2(v0, h0, l0); split2(v1, h1, l1);
            hs[k >> 1] = (unsigned)h0 | ((unsigned)h1 << 16);
            ls[k >> 1] = (unsigned)l0 | ((unsigned)l1 << 16);
        }
        uint4* dh4 = (uint4*)(hTHi + (size_t)rt * 128 + ch0);
        dh4[0] = make_uint4(hs[0], hs[1], hs[2], hs[3]);
        dh4[1] = make_uint4(hs[4], hs[5], hs[6], hs[7]);
        uint4* dl4 = (uint4*)(hTLo + (size_t)rt * 128 + ch0);
        dl4[0] = make_uint4(ls[0], ls[1], ls[2], ls[3]);
        dl4[1] = make_uint4(ls[4], ls[5], ls[6], ls[7]);
    } else {
        int i = (bid - 960) * 256 + tid;    // 60 blocks * 256 = 15360 float4
        ((float4*)lsacc)[i] = make_float4(0.f, 0.f, 0.f, 0.f);
    }
}

// ---------------------------------------------------------------------------
// conv + cond + gate via split-bf16 MFMA. Block: 128 gate-rows x 128 t.
// LDS slabs are CHUNK-MAJOR: addr(row,kc) = (row>>4)*1024 + kc*256 + (row&15)*16
// (achieved by lane = kc*16 + i source permutation; DMA dst stays linear).
// Fragment reads: 16 consecutive lanes -> consecutive 16B => conflict-free.
// ---------------------------------------------------------------------------
__global__ __launch_bounds__(256)
void conv_gate_mfma(const u16* __restrict__ hTHi, const u16* __restrict__ hTLo,
                    const u16* __restrict__ c2THi, const u16* __restrict__ c2TLo,
                    const u16* __restrict__ WcHi, const u16* __restrict__ WcLo,
                    const u16* __restrict__ WdHi, const u16* __restrict__ WdLo,
                    const float* __restrict__ fgb, const float* __restrict__ fgcb,
                    u16* __restrict__ oTHi, u16* __restrict__ oTLo,
                    const float* __restrict__ zbuf,
                    int dh, int dw, int rev)
{
    __shared__ char lds[32768];   // Ahi 0 | Alo 8K | Bhi 16K | Blo 24K
    const int tid = threadIdx.x;
    const int lane = tid & 63, w = tid >> 6;
    const int wm = w & 1, wn = w >> 1;
    const int t0 = blockIdx.x << 7;
    const int r  = blockIdx.y;
    const int ocb = blockIdx.z;
    const int si = lane & 15;        // row-within-16 (staging)
    const int sc = lane >> 4;        // k-chunk 0..3  (staging)

    f32x4 acc[4][4];
#pragma unroll
    for (int fm = 0; fm < 4; ++fm) {
        int ocx = (ocb << 6) + (wm << 5) + ((fm & 1) << 4) + ((lane >> 4) << 2) + ((fm >> 1) << 7);
        f32x4 b;
#pragma unroll
        for (int rg = 0; rg < 4; ++rg) b[rg] = fgb[ocx + rg] + fgcb[ocx + rg];
#pragma unroll
        for (int fn = 0; fn < 4; ++fn) acc[fm][fn] = b;
    }

    auto chunk = [&](const u16* aHi, const u16* aLo, int aStr,
                     const u16* bHi, const u16* bLo, int bStr,
                     int k0, int shift, int bounded) {
        __syncthreads();
#pragma unroll
        for (int e = 0; e < 2; ++e) {
            int rowA = (w << 5) + (e << 4) + si;     // block row 0..127
            int lb = (w << 11) + (e << 10);          // uniform LDS slab base
            gl_lds16(aHi + (size_t)rowA * aStr + k0 + sc * 8, lds + lb);
            gl_lds16(aLo + (size_t)rowA * aStr + k0 + sc * 8, lds + 8192 + lb);
            int cc = t0 + rowA + shift;
            const u16* sh = bHi + (size_t)cc * bStr + k0 + sc * 8;
            const u16* sl = bLo + (size_t)cc * bStr + k0 + sc * 8;
            if (bounded && (unsigned)cc >= 2048u) { sh = (const u16*)zbuf; sl = (const u16*)zbuf; }
            gl_lds16(sh, lds + 16384 + lb);
            gl_lds16(sl, lds + 24576 + lb);
        }
        __syncthreads();
        bf16x8 aF[4][2];
#pragma unroll
        for (int fm = 0; fm < 4; ++fm) {
            int off = (((wm << 2) + fm) << 10) + ((lane >> 4) << 8) + ((lane & 15) << 4);
            aF[fm][0] = *(const bf16x8*)(lds + off);
            aF[fm][1] = *(const bf16x8*)(lds + 8192 + off);
        }
#pragma unroll
        for (int fn = 0; fn < 4; ++fn) {
            int off = (((wn << 2) + fn) << 10) + ((lane >> 4) << 8) + ((lane & 15) << 4);
            bf16x8 bH = *(const bf16x8*)(lds + 16384 + off);
            bf16x8 bL = *(const bf16x8*)(lds + 24576 + off);
#pragma unroll
            for (int fm = 0; fm < 4; ++fm) {
                acc[fm][fn] = __builtin_amdgcn_mfma_f32_16x16x32_bf16(aF[fm][0], bH, acc[fm][fn], 0, 0, 0);
                acc[fm][fn] = __builtin_amdgcn_mfma_f32_16x16x32_bf16(aF[fm][1], bH, acc[fm][fn], 0, 0, 0);
                acc[fm][fn] = __builtin_amdgcn_mfma_f32_16x16x32_bf16(aF[fm][0], bL, acc[fm][fn], 0, 0, 0);
            }
        }
    };

    for (int tap = 0; tap < 9; ++tap) {
        int kh = tap / 3, kw = tap - kh * 3;
        int rr = r - (2 - kh) * dh;
        if (rr < 0) continue;                        // uniform per block
        int shift = (kw - 1) * dw;
        const u16* aHi = WcHi + ((size_t)tap * 256 + (size_t)ocb * 128) * 128;
        const u16* aLo = WcLo + ((size_t)tap * 256 + (size_t)ocb * 128) * 128;
        const u16* bHi = hTHi + (size_t)rr * 2048 * 128;
        const u16* bLo = hTLo + (size_t)rr * 2048 * 128;
        for (int icq = 0; icq < 4; ++icq)
            chunk(aHi, aLo, 128, bHi, bLo, 128, icq * 32, shift, 1);
    }
    {
        int rrow = rev ? (14 - r) : (r + 1);
        const u16* aHi = WdHi + (size_t)ocb * 128 * 96;
        const u16* aLo = WdLo + (size_t)ocb * 128 * 96;
        const u16* bHi = c2THi + (size_t)rrow * 2048 * 96;
        const u16* bLo = c2TLo + (size_t)rrow * 2048 * 96;
        for (int ccq = 0; ccq < 3; ++ccq)
            chunk(aHi, aLo, 96, bHi, bLo, 96, ccq * 32, 0, 0);
    }

    // gated activation (frag q = tanh rows, q+2 = sigmoid of same oc pairs)
    float ov[2][4][4];
#pragma unroll
    for (int q = 0; q < 2; ++q)
#pragma unroll
        for (int fn = 0; fn < 4; ++fn)
#pragma unroll
            for (int rg = 0; rg < 4; ++rg) {
                float tv = acc[q][fn][rg], sv = acc[q + 2][fn][rg];
                ov[q][fn][rg] = tanhf(tv) * (1.f / (1.f + expf(-sv)));
            }

    // LDS-transposed coalesced store of oT hi/lo [r][t][p]
#pragma unroll
    for (int pl = 0; pl < 2; ++pl) {
        __syncthreads();
#pragma unroll
        for (int q = 0; q < 2; ++q)
#pragma unroll
            for (int fn = 0; fn < 4; ++fn) {
                int tl = (wn << 6) + (fn << 4) + (lane & 15);
                int p0 = (wm << 5) + (q << 4) + ((lane >> 4) << 2);
                u16 s[4];
#pragma unroll
                for (int rg = 0; rg < 4; ++rg) {
                    float v = ov[q][fn][rg];
                    u16 hi = bfhi(v);
                    s[rg] = pl ? bfhi(v - bf2f(hi)) : hi;
                }
                uint2 val;
                val.x = (unsigned)s[0] | ((unsigned)s[1] << 16);
                val.y = (unsigned)s[2] | ((unsigned)s[3] << 16);
                *(uint2*)(lds + tl * 128 + ((p0 ^ ((tl & 7) << 3)) << 1)) = val;
            }
        __syncthreads();
        u16* dst = pl ? oTLo : oTHi;
#pragma unroll
        for (int e = 0; e < 4; ++e) {
            int tl = (tid >> 3) + (e << 5);
            int pg = tid & 7;
            uint4 v = *(const uint4*)(lds + tl * 128 + ((pg ^ (tl & 7)) << 4));
            *(uint4*)(dst + ((size_t)r * 2048 + t0 + tl) * 128 + (ocb << 6) + (pg << 3)) = v;
        }
    }
}

// ---------------------------------------------------------------------------
// h = (h + rs_w @ oact + b)*SQH  via split-bf16 MFMA; refresh hT hi/lo planes
// ---------------------------------------------------------------------------
__global__ __launch_bounds__(256)
void rs_mfma(float* __restrict__ h, const u16* __restrict__ oTHi, const u16* __restrict__ oTLo,
             const u16* __restrict__ WHi, const u16* __restrict__ WLo,
             const float* __restrict__ rsb,
             u16* __restrict__ hTHi, u16* __restrict__ hTLo)
{
    __shared__ char lds[24576];   // Ahi 0 | Alo 8K | Bhi 16K | Blo 20K
    const int tid = threadIdx.x;
    const int lane = tid & 63, w = tid >> 6;
    const int wm = w & 1, wn = w >> 1;
    const int t0 = blockIdx.x << 6;
    const int r = blockIdx.y;
    const int si = lane & 15, sc = lane >> 4;

    f32x4 acc[4][2];
#pragma unroll
    for (int fm = 0; fm < 4; ++fm)
#pragma unroll
        for (int fn = 0; fn < 2; ++fn)
#pragma unroll
            for (int rg = 0; rg < 4; ++rg) acc[fm][fn][rg] = 0.f;

    for (int icq = 0; icq < 4; ++icq) {
        int k0 = icq * 32;
        __syncthreads();
#pragma unroll
        for (int e = 0; e < 2; ++e) {
            int rowA = (w << 5) + (e << 4) + si;
            int lb = (w << 11) + (e << 10);
            gl_lds16(WHi + (size_t)rowA * 128 + k0 + sc * 8, lds + lb);
            gl_lds16(WLo + (size_t)rowA * 128 + k0 + sc * 8, lds + 8192 + lb);
        }
        {
            int tt = (w << 4) + si;
            int lb = (w << 10);
            gl_lds16(oTHi + ((size_t)r * 2048 + t0 + tt) * 128 + k0 + sc * 8, lds + 16384 + lb);
            gl_lds16(oTLo + ((size_t)r * 2048 + t0 + tt) * 128 + k0 + sc * 8, lds + 20480 + lb);
        }
        __syncthreads();
        bf16x8 aF[4][2];
#pragma unroll
        for (int fm = 0; fm < 4; ++fm) {
            int off = (((wm << 2) + fm) << 10) + ((lane >> 4) << 8) + ((lane & 15) << 4);
            aF[fm][0] = *(const bf16x8*)(lds + off);
            aF[fm][1] = *(const bf16x8*)(lds + 8192 + off);
        }
#pragma unroll
        for (int fn = 0; fn < 2; ++fn) {
            int off = (((wn << 1) + fn) << 10) + ((lane >> 4) << 8) + ((lane & 15) << 4);
            bf16x8 bH = *(const bf16x8*)(lds + 16384 + off);
            bf16x8 bL = *(const bf16x8*)(lds + 20480 + off);
#pragma unroll
            for (int fm = 0; fm < 4; ++fm) {
                acc[fm][fn] = __builtin_amdgcn_mfma_f32_16x16x32_bf16(aF[fm][0], bH, acc[fm][fn], 0, 0, 0);
                acc[fm][fn] = __builtin_amdgcn_mfma_f32_16x16x32_bf16(aF[fm][1], bH, acc[fm][fn], 0, 0, 0);
                acc[fm][fn] = __builtin_amdgcn_mfma_f32_16x16x32_bf16(aF[fm][0], bL, acc[fm][fn], 0, 0, 0);
            }
        }
    }

    float hv[4][2][4];
#pragma unroll
    for (int fm = 0; fm < 4; ++fm)
#pragma unroll
        for (int fn = 0; fn < 2; ++fn) {
            int t = t0 + (wn << 5) + (fn << 4) + (lane & 15);
#pragma unroll
            for (int rg = 0; rg < 4; ++rg) {
                int ch = (wm << 6) + (fm << 4) + ((lane >> 4) << 2) + rg;
                size_t off = (size_t)ch * 30720 + (size_t)r * 2048 + t;
                float nv = (h[off] + acc[fm][fn][rg] + rsb[ch]) * SQH;
                h[off] = nv;
                hv[fm][fn][rg] = nv;
            }
        }

#pragma unroll
    for (int pl = 0; pl < 2; ++pl) {
        __syncthreads();
#pragma unroll
        for (int fm = 0; fm < 4; ++fm)
#pragma unroll
            for (int fn = 0; fn < 2; ++fn) {
                int tl = (wn << 5) + (fn << 4) + (lane & 15);
                int ch0 = (wm << 6) + (fm << 4) + ((lane >> 4) << 2);
                u16 s[4];
#pragma unroll
                for (int rg = 0; rg < 4; ++rg) {
                    float v = hv[fm][fn][rg];
                    u16 hi = bfhi(v);
                    s[rg] = pl ? bfhi(v - bf2f(hi)) : hi;
                }
                uint2 val;
                val.x = (unsigned)s[0] | ((unsigned)s[1] << 16);
                val.y = (unsigned)s[2] | ((unsigned)s[3] << 16);
                *(uint2*)(lds + tl * 256 + ((ch0 ^ ((tl & 7) << 3)) << 1)) = val;
            }
        __syncthreads();
        u16* dst = pl ? hTLo : hTHi;
#pragma unroll
        for (int e = 0; e < 4; ++e) {
            int tl = (tid >> 4) + (e << 4);
            int chg = tid & 15;
            uint4 v = *(const uint4*)(lds + tl * 256 + ((chg ^ (tl & 7)) << 4));
            *(uint4*)(dst + ((size_t)r * 2048 + t0 + tl) * 128 + (chg << 3)) = v;
        }
    }
}

// lsacc += proj_w . (oT hi+lo)
__global__ void lsadd_k(float* __restrict__ lsacc, const u16* __restrict__ oTHi,
                        const u16* __restrict__ oTLo, const float* __restrict__ pw)
{
    int idx = blockIdx.x * 256 + threadIdx.x;   // 30720
    const uint4* ph = (const uint4*)(oTHi + (size_t)idx * 128);
    const uint4* pl = (const uint4*)(oTLo + (size_t)idx * 128);
    float a0 = 0.f, a1 = 0.f;
#pragma unroll 4
    for (int g = 0; g < 16; ++g) {
        uint4 vh = ph[g], vl = pl[g];
        const unsigned* uh = &vh.x; const unsigned* ul = &vl.x;
#pragma unroll
        for (int j = 0; j < 4; ++j) {
            int ic = g * 8 + j * 2;
            float v0 = bf2f((u16)(uh[j] & 0xffffu)) + bf2f((u16)(ul[j] & 0xffffu));
            float v1 = bf2f((u16)(uh[j] >> 16)) + bf2f((u16)(ul[j] >> 16));
            a0 = fmaf(pw[ic], v0, a0);       a0 = fmaf(pw[ic + 1], v1, a0);
            a1 = fmaf(pw[128 + ic], v0, a1); a1 = fmaf(pw[128 + ic + 1], v1, a1);
        }
    }
    lsacc[idx] += a0;
    lsacc[30720 + idx] += a1;
}

// affine coupling + folded reversal + logdet
__global__ void update_k(const float* __restrict__ Xc, float* __restrict__ Xn,
                         const float* __restrict__ lsacc, const float* __restrict__ pb,
                         const float* __restrict__ psc, float* __restrict__ logdet)
{
    int idx = blockIdx.x * 256 + threadIdx.x;   // 30720
    int rr = idx >> 11, t = idx & 2047;
    float e0 = expf(3.f * psc[0]), e1 = expf(3.f * psc[1]);
    float ls0 = (lsacc[idx] + pb[0]) * e0;
    float ls1 = (lsacc[30720 + idx] + pb[1]) * e1;
    float xn = fmaf(Xc[idx + 2048], expf(ls0), ls1);
    Xn[(14 - rr) * 2048 + t] = xn;
    if (idx < 2048) Xn[15 * 2048 + idx] = Xc[idx];
    float s = ls0;
#pragma unroll
    for (int o = 32; o > 0; o >>= 1) s += __shfl_down(s, o);
    if ((threadIdx.x & 63) == 0) atomicAdd(logdet, s);
}

// ---------------------------------------------------------------------------
extern "C" void kernel_launch(void* const* d_in, const int* in_sizes, int n_in,
                              void* d_out, int out_size, void* d_ws, size_t ws_size,
                              hipStream_t stream)
{
    const float* x       = (const float*)d_in[0];
    const float* c       = (const float*)d_in[1];
    const float* front_w = (const float*)d_in[2];
    const float* front_b = (const float*)d_in[3];
    const float* fg_w    = (const float*)d_in[4];
    const float* fg_b    = (const float*)d_in[5];
    const float* fgc_w   = (const float*)d_in[6];
    const float* fgc_b   = (const float*)d_in[7];
    const float* rs_w    = (const float*)d_in[8];
    const float* rs_b    = (const float*)d_in[9];
    const float* proj_w  = (const float*)d_in[10];
    const float* proj_b  = (const float*)d_in[11];
    const float* proj_s  = (const float*)d_in[12];
    const float* up_w1   = (const float*)d_in[13];
    const float* up_b1   = (const float*)d_in[14];
    const float* up_w2   = (const float*)d_in[15];
    const float* up_b2   = (const float*)d_in[16];
    float* out = (float*)d_out;

    float* base = (float*)d_ws;
    float* c1   = base;                  // 163840
    float* cup  = c1 + 163840;           // 2621440
    float* lsac = cup + 2621440;         // 61440
    float* outA = lsac + 61440;          // 32768
    float* outB = outA + 32768;          // 32768
    float* zbuf = outB + 32768;          // 64
    float* h    = zbuf + 64;             // 3932160
    u16* u = (u16*)(h + 3932160);
    u16* hTHi = u;  u += 3932160;
    u16* hTLo = u;  u += 3932160;
    u16* oTHi = u;  u += 3932160;
    u16* oTLo = u;  u += 3932160;
    u16* c2THi = u; u += 3145728;
    u16* c2TLo = u; u += 3145728;
    u16* WdHi = u;  u += 1572864;
    u16* WdLo = u;  u += 1572864;
    u16* WrsHi = u; u += 1048576;
    u16* WrsLo = u; u += 1048576;
    u16* WcHi = u;  u += 2359296;
    u16* WcLo = u;  u += 2359296;

    upsample_k<<<640, 256, 0, stream>>>(c, 128, up_w1, up_b1, c1, 2048);
    upsample_k<<<10240, 256, 0, stream>>>(c1, 2048, up_w2, up_b2, cup, 32768);
    c2t_k<<<12288, 256, 0, stream>>>(cup, c2THi, c2TLo);
    squeeze_x_k<<<128, 256, 0, stream>>>(x, outA);
    zero2_k<<<1, 64, 0, stream>>>(out + 32768, zbuf);
    wd_cvt_k<<<6144, 256, 0, stream>>>(fgc_w, WdHi, WdLo);
    wrs_cvt_k<<<4096, 256, 0, stream>>>(rs_w, WrsHi, WrsLo);

    float* Xc = outA;
    float* Xn = outB;
    for (int i = 0; i < 8; ++i) {
        int rev = i & 1;
        wc_cvt_k<<<1024, 256, 0, stream>>>(fg_w + (size_t)i * 2359296, WcHi, WcLo);
        front_k<<<1020, 256, 0, stream>>>(Xc, h, hTHi, hTLo,
                                          front_w + i * 128, front_b + i * 128, lsac);
        for (int l = 0; l < 8; ++l) {
            int fl = i * 8 + l;
            int dh = 1 << (l % 3), dw = 1 << l;
            conv_gate_mfma<<<dim3(16, 15, 2), 256, 0, stream>>>(
                hTHi, hTLo, c2THi, c2TLo,
                WcHi + (size_t)l * 9 * 256 * 128, WcLo + (size_t)l * 9 * 256 * 128,
                WdHi + (size_t)fl * 256 * 96, WdLo + (size_t)fl * 256 * 96,
                fg_b + fl * 256, fgc_b + fl * 256,
                oTHi, oTLo, zbuf, dh, dw, rev);
            lsadd_k<<<120, 256, 0, stream>>>(lsac, oTHi, oTLo, proj_w + i * 256);
            if (l < 7)
                rs_mfma<<<dim3(32, 15), 256, 0, stream>>>(h, oTHi, oTLo,
                    WrsHi + (size_t)fl * 16384, WrsLo + (size_t)fl * 16384,
                    rs_b + fl * 128, hTHi, hTLo);
        }
        float* dst = (i == 7) ? out : Xn;
        update_k<<<120, 256, 0, stream>>>(Xc, dst, lsac, proj_b + i * 2,
                                          proj_s + i * 2, out + 32768);
        float* tmp = Xc; Xc = Xn; Xn = tmp;
    }
}